// Round 9
// baseline (35.660 us; speedup 1.0000x reference)
//
#include <hip/hip_runtime.h>
#include <hip/hip_bf16.h>
#include <float.h>

// Problem constants (from reference setup_inputs)
#define B_  4
#define C_  256
#define H_  50
#define W_  50
#define R_  300
#define PH_ 7
#define PW_ 7
#define S_  (H_ * W_)        // 2500
#define Q_  (PH_ * PW_)      // 49
#define SC_ (S_ * C_)        // 640000 floats per batch image
#define C2_ 128              // channel-pairs (float2 lanes)
#define NWG2 (R_ * 2)        // 600 pool blocks (divisible by 8)

// ---------------------------------------------------------------------------
// Kernel K1: transpose fm [B,C,S] -> fmT [B,S,C] AND build span tables
//   P2[b,s,c] = max over w..min(w+1, W-1) (row-clamped) of fm
//   P4[b,s,c] = max over w..min(w+3, W-1) (row-clamped) of fm
// 64 s-cols (+4 halo) x 64 channels per block; LDS stride 69 (odd, conflict-
// free both phases). Row-clamp => never reads cross-row or invalid columns.
// ---------------------------------------------------------------------------
__global__ __launch_bounds__(256) void transpose_tables(
    const float* __restrict__ fm,   // [B, C, S]
    float* __restrict__ fmT,        // [B, S, C]
    float* __restrict__ P2,         // [B, S, C]
    float* __restrict__ P4)         // [B, S, C]
{
    __shared__ float tile[64][69];

    const int b  = blockIdx.z;
    const int c0 = blockIdx.y * 64;           // 256/64 = 4
    const int s0 = blockIdx.x * 64;           // ceil(2500/64) = 40

    const int tx = threadIdx.x;               // 0..63 (lane)
    const int ty = threadIdx.y;               // 0..3  (wave)

    if (s0 + tx < S_) {
        #pragma unroll
        for (int j = 0; j < 16; ++j) {
            const int c = c0 + ty + j * 4;
            tile[ty + j * 4][tx] = fm[((size_t)b * C_ + c) * S_ + (s0 + tx)];
        }
    }
    if (tx < 4 && s0 + 64 + tx < S_) {
        #pragma unroll
        for (int j = 0; j < 16; ++j) {
            const int c = c0 + ty + j * 4;
            tile[ty + j * 4][64 + tx] = fm[((size_t)b * C_ + c) * S_ + (s0 + 64 + tx)];
        }
    }
    __syncthreads();

    #pragma unroll
    for (int j = 0; j < 16; ++j) {
        const int s = s0 + ty + j * 4;
        if (s < S_) {
            const int ls  = ty + j * 4;
            const int w   = s % W_;                    // wave-uniform
            const int rem = W_ - 1 - w;                // valid same-row nbrs
            const float v0 = tile[tx][ls];
            float p2 = (rem >= 1) ? fmaxf(v0, tile[tx][ls + 1]) : v0;
            float p4 = p2;
            if (rem >= 2) p4 = fmaxf(p4, tile[tx][ls + 2]);
            if (rem >= 3) p4 = fmaxf(p4, tile[tx][ls + 3]);

            const size_t o = ((size_t)b * S_ + s) * C_ + (c0 + tx);
            fmT[o] = v0;
            P2[o]  = p2;
            P4[o]  = p4;
        }
    }
}

// ---------------------------------------------------------------------------
// Block-uniform ROI decode (SPATIAL_SCALE == 1.0); matches reference exactly.
// ---------------------------------------------------------------------------
__device__ __forceinline__ void roi_decode(const float* __restrict__ rois, int r,
                                           int& b, int& x0, int& y0,
                                           int& roi_w, int& roi_h)
{
    const float* rp = rois + r * 5;
    b = (int)rp[4];                          // trunc, matches astype(int32)
    // jnp.round == round-half-to-even == rintf
    x0      = (int)rintf(rp[0]);
    y0      = (int)rintf(rp[1]);
    int x1  = (int)rintf(rp[2]);
    int y1  = (int)rintf(rp[3]);
    x0 = min(max(x0, 0), W_ - 1);
    x1 = min(max(x1, 0), W_ - 1);
    y0 = min(max(y0, 0), H_ - 1);
    y1 = min(max(y1, 0), H_ - 1);
    x1 = max(x1, x0 + 1);
    y1 = max(y1, y0 + 1);
    roi_w = x1 - x0;                         // >= 1  (bin widths  <= 8)
    roi_h = y1 - y0;                         // >= 1  (bin heights <= 8)
}

// ---------------------------------------------------------------------------
// Branchless per-bin pooling on float2 lanes. WH = block-uniform max bin
// height (template). Width via span tables: sp = 4/2/1 -> anchors ws and
// we-sp cover exactly [ws,we) for any ww 1..8. Rows: min(hs+kh, he-1) clamp
// -> in-window duplicates, max unchanged. Outer loop unroll 2 -> <= 32
// float2 loads in flight (no spill), ~3-4 latency exposures per wave.
// q = wv + 8k: each bin owned by exactly one wave; guard is wave-uniform.
// ---------------------------------------------------------------------------
template<int WH>
__device__ __forceinline__ void pool_bins2(
    const float2* __restrict__ t1, const float2* __restrict__ t2,
    const float2* __restrict__ t4, float2* __restrict__ buf2,
    int wv, int lane, size_t laneOff,
    int x0, int y0, int roi_w, int roi_h)
{
    #pragma unroll 2
    for (int k = 0; k < 7; ++k) {
        const int q = wv + 8 * k;
        if (q < Q_) {                        // wave-uniform
            const int ph = q / PW_;
            const int pw = q - ph * PW_;
            const int ws = x0 + (pw * roi_w) / PW_;
            const int we = x0 + ((pw + 1) * roi_w + PW_ - 1) / PW_;
            const int hs = y0 + (ph * roi_h) / PH_;
            const int he = y0 + ((ph + 1) * roi_h + PH_ - 1) / PH_;
            const int ww = we - ws;          // 1..8

            const int sp = (ww >= 4) ? 4 : ((ww >= 2) ? 2 : 1);
            const float2* tb = (ww >= 4) ? t4 : ((ww >= 2) ? t2 : t1);
            const int colB = we - sp;

            float2 va[WH], vb[WH];
            #pragma unroll
            for (int kh = 0; kh < WH; ++kh) {
                int row = hs + kh;
                row = (row > he - 1) ? (he - 1) : row;     // clamp (in-window)
                const size_t ro = laneOff + (size_t)(row * W_) * C2_;
                va[kh] = tb[ro + (size_t)ws * C2_];
                vb[kh] = tb[ro + (size_t)colB * C2_];
            }
            float mx = -FLT_MAX, my = -FLT_MAX;
            #pragma unroll
            for (int kh = 0; kh < WH; ++kh) {
                mx = fmaxf(mx, fmaxf(va[kh].x, vb[kh].x));
                my = fmaxf(my, fmaxf(va[kh].y, vb[kh].y));
            }
            buf2[q * 65 + lane] = make_float2(mx, my);
        }
    }
}

// ---------------------------------------------------------------------------
// Kernel K2: fused pool. Block = (roi, 128-ch half) -> 600 blocks, 512 thr
// (8 waves). Lane = channel-pair (float2). whmax (exact, block-uniform)
// selects a fully-unrolled instantiation. Staged in padded LDS float2[49][65];
// block-exclusive contiguous 25 KB write out[r, h*128..+128, :].
// ---------------------------------------------------------------------------
__global__ __launch_bounds__(512) void roi_pool_tables2(
    const float* __restrict__ fmT,   // [B, S, C]
    const float* __restrict__ P2,    // [B, S, C]
    const float* __restrict__ P4,    // [B, S, C]
    const float* __restrict__ rois,  // [R, 5]
    float* __restrict__ out)         // [R, C, Q]
{
    __shared__ float2 buf2[Q_ * 65];         // 25480 B

    // XCD-chunked swizzle (600 % 8 == 0 -> bijective): both halves of an ROI
    // + ~37 neighboring ROIs share one XCD's L2 copy of the table lines.
    const int bid = blockIdx.x;
    const int swz = (bid & 7) * (NWG2 / 8) + (bid >> 3);
    const int r   = swz >> 1;
    const int hh  = swz & 1;                 // channel half 0/1

    const int t    = threadIdx.x;
    const int wv   = t >> 6;                 // wave 0..7
    const int lane = t & 63;                 // channel-pair within half

    int b, x0, y0, roi_w, roi_h;
    roi_decode(rois, r, b, x0, y0, roi_w, roi_h);

    // exact block-uniform max bin height
    int whmax = 1;
    #pragma unroll
    for (int i = 0; i < PH_; ++i) {
        const int hs = (i * roi_h) / PH_;
        const int he = ((i + 1) * roi_h + PH_ - 1) / PH_;
        whmax = max(whmax, he - hs);
    }

    // float2 element offset: ((b*S + s)*C + c)/2 with c = hh*128 + 2*lane
    const size_t laneOff = (size_t)b * (S_ * C2_) + (size_t)(hh * 64 + lane);
    const float2* t1 = (const float2*)fmT;
    const float2* t2 = (const float2*)P2;
    const float2* t4 = (const float2*)P4;

    switch (whmax) {                         // block-uniform dispatch
        case 1: pool_bins2<1>(t1, t2, t4, buf2, wv, lane, laneOff, x0, y0, roi_w, roi_h); break;
        case 2: pool_bins2<2>(t1, t2, t4, buf2, wv, lane, laneOff, x0, y0, roi_w, roi_h); break;
        case 3: pool_bins2<3>(t1, t2, t4, buf2, wv, lane, laneOff, x0, y0, roi_w, roi_h); break;
        case 4: pool_bins2<4>(t1, t2, t4, buf2, wv, lane, laneOff, x0, y0, roi_w, roi_h); break;
        case 5: pool_bins2<5>(t1, t2, t4, buf2, wv, lane, laneOff, x0, y0, roi_w, roi_h); break;
        case 6: pool_bins2<6>(t1, t2, t4, buf2, wv, lane, laneOff, x0, y0, roi_w, roi_h); break;
        case 7: pool_bins2<7>(t1, t2, t4, buf2, wv, lane, laneOff, x0, y0, roi_w, roi_h); break;
        default: pool_bins2<8>(t1, t2, t4, buf2, wv, lane, laneOff, x0, y0, roi_w, roi_h); break;
    }
    __syncthreads();

    // block-exclusive coalesced write: out[r, hh*128 .. +128, 0..49) = 25 KB
    float* outp = out + ((size_t)r * C_ + hh * C2_) * Q_;
    const float* bufs = (const float*)buf2;
    #pragma unroll
    for (int k = 0; k < 13; ++k) {           // ceil(128*49 / 512) = 13
        const int e = k * 512 + t;
        if (e < C2_ * Q_) {
            const int cl = e / Q_;           // 0..127 (scalar channel)
            const int q  = e - cl * Q_;
            outp[e] = bufs[(q * 65 + (cl >> 1)) * 2 + (cl & 1)];
        }
    }
}

// ---------------------------------------------------------------------------
// Fallback (ws too small for the 3 tables): round-1 thread-per-output kernel
// (proven, 42.7 us).
// ---------------------------------------------------------------------------
__global__ __launch_bounds__(256) void roi_pool_naive(
    const float* __restrict__ fm,    // [B, C, H, W]
    const float* __restrict__ rois,
    float* __restrict__ out)
{
    const int total = R_ * C_ * Q_;
    int t = blockIdx.x * blockDim.x + threadIdx.x;
    if (t >= total) return;
    int q   = t % Q_;
    int tmp = t / Q_;
    int pw  = q % PW_;
    int ph  = q / PW_;
    int c   = tmp % C_;
    int r   = tmp / C_;

    int b, x0, y0, roi_w, roi_h;
    roi_decode(rois, r, b, x0, y0, roi_w, roi_h);

    const int ws = x0 + (pw * roi_w) / PW_;
    const int we = x0 + ((pw + 1) * roi_w + PW_ - 1) / PW_;
    const int hs = y0 + (ph * roi_h) / PH_;
    const int he = y0 + ((ph + 1) * roi_h + PH_ - 1) / PH_;

    const float* p = fm + ((size_t)(b * C_ + c)) * S_;
    float m = -FLT_MAX;
    for (int h = hs; h < he; ++h)
        for (int w = ws; w < we; ++w)
            m = fmaxf(m, p[h * W_ + w]);
    out[t] = m;
}

extern "C" void kernel_launch(void* const* d_in, const int* in_sizes, int n_in,
                              void* d_out, int out_size, void* d_ws, size_t ws_size,
                              hipStream_t stream)
{
    const float* fm   = (const float*)d_in[0];  // [4,256,50,50]
    const float* rois = (const float*)d_in[1];  // [300,5]
    float* out        = (float*)d_out;          // [300,256,7,7]

    const size_t ARR  = (size_t)B_ * SC_;                // 2,560,000 floats
    const size_t NEED = 3 * ARR * sizeof(float);         // 30.72 MB

    if (ws_size >= NEED) {
        float* fmT = (float*)d_ws;
        float* P2  = fmT + ARR;
        float* P4  = P2 + ARR;
        {
            dim3 grid((S_ + 63) / 64, C_ / 64, B_);      // (40, 4, 4)
            dim3 block(64, 4, 1);
            transpose_tables<<<grid, block, 0, stream>>>(fm, fmT, P2, P4);
        }
        roi_pool_tables2<<<NWG2, 512, 0, stream>>>(fmT, P2, P4, rois, out);
    } else {
        const int total = R_ * C_ * Q_;
        roi_pool_naive<<<(total + 255) / 256, 256, 0, stream>>>(fm, rois, out);
    }
}

// Round 10
// 33.695 us; speedup vs baseline: 1.0583x; 1.0583x over previous
//
#include <hip/hip_runtime.h>
#include <hip/hip_bf16.h>
#include <float.h>

// Problem constants (from reference setup_inputs)
#define B_  4
#define C_  256
#define H_  50
#define W_  50
#define R_  300
#define PH_ 7
#define PW_ 7
#define S_  (H_ * W_)        // 2500
#define Q_  (PH_ * PW_)      // 49
#define SC_ (S_ * C_)        // 640000 floats per batch image
#define CQ_  64              // channels per pool block
#define NCQ  (C_ / CQ_)      // 4
#define NWG_POOL (R_ * NCQ)  // 1200 (divisible by 8)

// ---------------------------------------------------------------------------
// Kernel K1: transpose fm [B,C,S] -> fmT [B,S,C] AND build span tables
//   P2[b,s,c] = max over w..min(w+1, W-1) (row-clamped) of fm
//   P4[b,s,c] = max over w..min(w+3, W-1) (row-clamped) of fm
// 64 s-cols (+4 halo) x 64 channels per block; LDS stride 69 (odd, conflict-
// free both phases). Row-clamp => never reads cross-row or invalid columns.
// ---------------------------------------------------------------------------
__global__ __launch_bounds__(256) void transpose_tables(
    const float* __restrict__ fm,   // [B, C, S]
    float* __restrict__ fmT,        // [B, S, C]
    float* __restrict__ P2,         // [B, S, C]
    float* __restrict__ P4)         // [B, S, C]
{
    __shared__ float tile[64][69];

    const int b  = blockIdx.z;
    const int c0 = blockIdx.y * 64;           // 256/64 = 4
    const int s0 = blockIdx.x * 64;           // ceil(2500/64) = 40

    const int tx = threadIdx.x;               // 0..63 (lane)
    const int ty = threadIdx.y;               // 0..3  (wave)

    if (s0 + tx < S_) {
        #pragma unroll
        for (int j = 0; j < 16; ++j) {
            const int c = c0 + ty + j * 4;
            tile[ty + j * 4][tx] = fm[((size_t)b * C_ + c) * S_ + (s0 + tx)];
        }
    }
    if (tx < 4 && s0 + 64 + tx < S_) {
        #pragma unroll
        for (int j = 0; j < 16; ++j) {
            const int c = c0 + ty + j * 4;
            tile[ty + j * 4][64 + tx] = fm[((size_t)b * C_ + c) * S_ + (s0 + 64 + tx)];
        }
    }
    __syncthreads();

    #pragma unroll
    for (int j = 0; j < 16; ++j) {
        const int s = s0 + ty + j * 4;
        if (s < S_) {
            const int ls  = ty + j * 4;
            const int w   = s % W_;                    // wave-uniform
            const int rem = W_ - 1 - w;                // valid same-row nbrs
            const float v0 = tile[tx][ls];
            float p2 = (rem >= 1) ? fmaxf(v0, tile[tx][ls + 1]) : v0;
            float p4 = p2;
            if (rem >= 2) p4 = fmaxf(p4, tile[tx][ls + 2]);
            if (rem >= 3) p4 = fmaxf(p4, tile[tx][ls + 3]);

            const size_t o = ((size_t)b * S_ + s) * C_ + (c0 + tx);
            fmT[o] = v0;
            P2[o]  = p2;
            P4[o]  = p4;
        }
    }
}

// ---------------------------------------------------------------------------
// Block-uniform ROI decode (SPATIAL_SCALE == 1.0); matches reference exactly.
// ---------------------------------------------------------------------------
__device__ __forceinline__ void roi_decode(const float* __restrict__ rois, int r,
                                           int& b, int& x0, int& y0,
                                           int& roi_w, int& roi_h)
{
    const float* rp = rois + r * 5;
    b = (int)rp[4];                          // trunc, matches astype(int32)
    // jnp.round == round-half-to-even == rintf
    x0      = (int)rintf(rp[0]);
    y0      = (int)rintf(rp[1]);
    int x1  = (int)rintf(rp[2]);
    int y1  = (int)rintf(rp[3]);
    x0 = min(max(x0, 0), W_ - 1);
    x1 = min(max(x1, 0), W_ - 1);
    y0 = min(max(y0, 0), H_ - 1);
    y1 = min(max(y1, 0), H_ - 1);
    x1 = max(x1, x0 + 1);
    y1 = max(y1, y0 + 1);
    roi_w = x1 - x0;                         // >= 1  (bin widths  <= 8)
    roi_h = y1 - y0;                         // >= 1  (bin heights <= 8)
}

// ---------------------------------------------------------------------------
// Branchless per-bin pooling, WH = block-uniform max bin height (template).
// Width via span tables: sp = 4/2/1 -> anchors ws and we-sp cover exactly
// [ws,we) for any ww 1..8. Rows: min(hs+kh, he-1) clamp -> in-window
// duplicates, max unchanged. UNROLL 2 (not 13): <= 32 values in flight ->
// no scratch spills, ~2 latency exposures deep, VGPR low -> high occupancy.
// All offset arithmetic int32 (max offset < 2.56M, provably fits).
// Bin->wave: contiguous ranges w0:0-12, w1:13-24, w2:25-36, w3:37-48; the
// within-wave clamp re-computes the wave's own last bin (same LDS value,
// no cross-wave aliasing).
// ---------------------------------------------------------------------------
template<int WH>
__device__ __forceinline__ void pool_bins(
    const float* __restrict__ fmT, const float* __restrict__ P2,
    const float* __restrict__ P4, float* __restrict__ buf,
    int wv, int lane, int imgC,
    int x0, int y0, int roi_w, int roi_h)
{
    const int start = wv * 12 + (wv ? 1 : 0);
    const int qlast = wv * 12 + 12;

    #pragma unroll 2
    for (int k = 0; k < 13; ++k) {
        int q = start + k;
        q = (q > qlast) ? qlast : q;
        const int ph = q / PW_;
        const int pw = q - ph * PW_;
        const int ws = x0 + (pw * roi_w) / PW_;
        const int we = x0 + ((pw + 1) * roi_w + PW_ - 1) / PW_;
        const int hs = y0 + (ph * roi_h) / PH_;
        const int he = y0 + ((ph + 1) * roi_h + PH_ - 1) / PH_;
        const int ww = we - ws;              // 1..8

        const int sp = (ww >= 4) ? 4 : ((ww >= 2) ? 2 : 1);
        const float* tb = (ww >= 4) ? P4 : ((ww >= 2) ? P2 : fmT);
        const int colB = we - sp;

        float va[WH], vb[WH];
        #pragma unroll
        for (int kh = 0; kh < WH; ++kh) {
            int row = hs + kh;
            row = (row > he - 1) ? (he - 1) : row;        // clamp (in-window)
            const int ro = imgC + row * (W_ * C_);
            va[kh] = tb[ro + ws * C_];
            vb[kh] = tb[ro + colB * C_];
        }
        float m = -FLT_MAX;
        #pragma unroll
        for (int kh = 0; kh < WH; ++kh)
            m = fmaxf(m, fmaxf(va[kh], vb[kh]));

        buf[q * 65 + lane] = m;
    }
}

// ---------------------------------------------------------------------------
// Kernel K2: fused pool. Block = (roi, 64-ch quarter) -> 1200 blocks, 4 waves.
// whmax (exact, block-uniform) selects a fully-unrolled instantiation.
// Staged in padded LDS [49][65]; block-exclusive contiguous 12.5 KB write.
// ---------------------------------------------------------------------------
__global__ __launch_bounds__(256) void roi_pool_tables(
    const float* __restrict__ fmT,   // [B, S, C]
    const float* __restrict__ P2,    // [B, S, C]
    const float* __restrict__ P4,    // [B, S, C]
    const float* __restrict__ rois,  // [R, 5]
    float* __restrict__ out)         // [R, C, Q]
{
    __shared__ float buf[Q_ * 65];           // 12740 B

    // XCD-chunked swizzle (1200 % 8 == 0 -> bijective)
    const int bid = blockIdx.x;
    const int swz = (bid & 7) * (NWG_POOL / 8) + (bid >> 3);
    const int r   = swz >> 2;
    const int c0  = (swz & (NCQ - 1)) * CQ_;

    const int t    = threadIdx.x;
    const int wv   = t >> 6;
    const int lane = t & 63;

    int b, x0, y0, roi_w, roi_h;
    roi_decode(rois, r, b, x0, y0, roi_w, roi_h);

    // exact block-uniform max bin height
    int whmax = 1;
    #pragma unroll
    for (int i = 0; i < PH_; ++i) {
        const int hs = (i * roi_h) / PH_;
        const int he = ((i + 1) * roi_h + PH_ - 1) / PH_;
        whmax = max(whmax, he - hs);
    }

    const int imgC = b * SC_ + c0 + lane;    // < 2.56M, fits int32

    switch (whmax) {                         // block-uniform dispatch
        case 1: pool_bins<1>(fmT, P2, P4, buf, wv, lane, imgC, x0, y0, roi_w, roi_h); break;
        case 2: pool_bins<2>(fmT, P2, P4, buf, wv, lane, imgC, x0, y0, roi_w, roi_h); break;
        case 3: pool_bins<3>(fmT, P2, P4, buf, wv, lane, imgC, x0, y0, roi_w, roi_h); break;
        case 4: pool_bins<4>(fmT, P2, P4, buf, wv, lane, imgC, x0, y0, roi_w, roi_h); break;
        case 5: pool_bins<5>(fmT, P2, P4, buf, wv, lane, imgC, x0, y0, roi_w, roi_h); break;
        case 6: pool_bins<6>(fmT, P2, P4, buf, wv, lane, imgC, x0, y0, roi_w, roi_h); break;
        case 7: pool_bins<7>(fmT, P2, P4, buf, wv, lane, imgC, x0, y0, roi_w, roi_h); break;
        default: pool_bins<8>(fmT, P2, P4, buf, wv, lane, imgC, x0, y0, roi_w, roi_h); break;
    }
    __syncthreads();

    // block-exclusive coalesced write: out[r, c0..c0+64, 0..49)
    float* outp = out + ((size_t)r * C_ + c0) * Q_;
    #pragma unroll
    for (int k = 0; k < 13; ++k) {
        const int e = k * 256 + t;
        if (e < CQ_ * Q_) {
            const int cl = e / Q_;
            const int q  = e - cl * Q_;
            outp[e] = buf[q * 65 + cl];
        }
    }
}

// ---------------------------------------------------------------------------
// Fallback (ws too small for the 3 tables): round-1 thread-per-output kernel
// (proven, 42.7 us).
// ---------------------------------------------------------------------------
__global__ __launch_bounds__(256) void roi_pool_naive(
    const float* __restrict__ fm,    // [B, C, H, W]
    const float* __restrict__ rois,
    float* __restrict__ out)
{
    const int total = R_ * C_ * Q_;
    int t = blockIdx.x * blockDim.x + threadIdx.x;
    if (t >= total) return;
    int q   = t % Q_;
    int tmp = t / Q_;
    int pw  = q % PW_;
    int ph  = q / PW_;
    int c   = tmp % C_;
    int r   = tmp / C_;

    int b, x0, y0, roi_w, roi_h;
    roi_decode(rois, r, b, x0, y0, roi_w, roi_h);

    const int ws = x0 + (pw * roi_w) / PW_;
    const int we = x0 + ((pw + 1) * roi_w + PW_ - 1) / PW_;
    const int hs = y0 + (ph * roi_h) / PH_;
    const int he = y0 + ((ph + 1) * roi_h + PH_ - 1) / PH_;

    const float* p = fm + ((size_t)(b * C_ + c)) * S_;
    float m = -FLT_MAX;
    for (int h = hs; h < he; ++h)
        for (int w = ws; w < we; ++w)
            m = fmaxf(m, p[h * W_ + w]);
    out[t] = m;
}

extern "C" void kernel_launch(void* const* d_in, const int* in_sizes, int n_in,
                              void* d_out, int out_size, void* d_ws, size_t ws_size,
                              hipStream_t stream)
{
    const float* fm   = (const float*)d_in[0];  // [4,256,50,50]
    const float* rois = (const float*)d_in[1];  // [300,5]
    float* out        = (float*)d_out;          // [300,256,7,7]

    const size_t ARR  = (size_t)B_ * SC_;                // 2,560,000 floats
    const size_t NEED = 3 * ARR * sizeof(float);         // 30.72 MB

    if (ws_size >= NEED) {
        float* fmT = (float*)d_ws;
        float* P2  = fmT + ARR;
        float* P4  = P2 + ARR;
        {
            dim3 grid((S_ + 63) / 64, C_ / 64, B_);      // (40, 4, 4)
            dim3 block(64, 4, 1);
            transpose_tables<<<grid, block, 0, stream>>>(fm, fmT, P2, P4);
        }
        roi_pool_tables<<<NWG_POOL, 256, 0, stream>>>(fmT, P2, P4, rois, out);
    } else {
        const int total = R_ * C_ * Q_;
        roi_pool_naive<<<(total + 255) / 256, 256, 0, stream>>>(fm, rois, out);
    }
}